// Round 10
// baseline (82.311 us; speedup 1.0000x reference)
//
#include <hip/hip_runtime.h>

#define QTOT 12240
#define KD   256

typedef float f32x4 __attribute__((ext_vector_type(4)));
typedef short s16x8 __attribute__((ext_vector_type(8)));
typedef short s16x4 __attribute__((ext_vector_type(4)));
typedef unsigned short ushort_t;

__device__ __forceinline__ unsigned short f2b(float x) {
    union { float f; unsigned u; } c; c.f = x;
    unsigned r = c.u + 0x7fffu + ((c.u >> 16) & 1u);
    return (unsigned short)(r >> 16);
}
__device__ __forceinline__ float b2f(unsigned short u) {
    return __uint_as_float((unsigned)u << 16);
}
// LDS row: 512B, XOR bits 4-6 of k-byte with row&7 (write & read sides)
__device__ __forceinline__ int swz(int row, int kb) { return row * 512 + (kb ^ ((row & 7) << 4)); }

// ---------------------------------------------------------------------------
// prep2: coalesced weight transpose via 32x32 LDS tiles + combined bias.
// blocks 0..63 WvT, 64..159 WcT, 160..223 WoT, 224 bias.
// ---------------------------------------------------------------------------
__global__ __launch_bounds__(256) void prep2(
    const float* __restrict__ W_val, const float* __restrict__ W_off,
    const float* __restrict__ W_attn, const float* __restrict__ W_out,
    const float* __restrict__ b_off, const float* __restrict__ b_attn,
    ushort_t* __restrict__ WvT, ushort_t* __restrict__ WcT,
    ushort_t* __restrict__ WoT, float* __restrict__ bcomb)
{
    const int b = blockIdx.x;
    if (b == 224) {
        for (int t = threadIdx.x; t < 384; t += 256)
            bcomb[t] = (t < 256) ? b_off[t] : b_attn[t - 256];
        return;
    }
    __shared__ ushort_t tile[32][33];
    const float* src; ushort_t* dst; int kt, nt, srcld, n_off;
    if (b < 64)       { src = W_val; dst = WvT; kt = b >> 3;        nt = b & 7;        srcld = 256; n_off = 0; }
    else if (b < 160) { int t = b - 64; dst = WcT; kt = t / 12;     nt = t % 12;
                        if (nt < 8) { src = W_off;  srcld = 256; n_off = 0; }
                        else        { src = W_attn; srcld = 128; n_off = 256; } }
    else              { int t = b - 160; src = W_out; dst = WoT; kt = t >> 3; nt = t & 7; srcld = 256; n_off = 0; }

    {   // read 32x32 tile, rows coalesced
        const int r = threadIdx.x >> 3, c4 = (threadIdx.x & 7) * 4;
        const int gk = kt * 32 + r;
        const int gs = nt * 32 + c4 - n_off;
        float4 f = *(const float4*)(src + (size_t)gk * srcld + gs);
        tile[r][c4 + 0] = f2b(f.x); tile[r][c4 + 1] = f2b(f.y);
        tile[r][c4 + 2] = f2b(f.z); tile[r][c4 + 3] = f2b(f.w);
    }
    __syncthreads();
    {   // write transposed, rows coalesced
        const int r2 = threadIdx.x >> 3, k4 = (threadIdx.x & 7) * 4;
        s16x4 v;
        v[0] = tile[k4 + 0][r2]; v[1] = tile[k4 + 1][r2];
        v[2] = tile[k4 + 2][r2]; v[3] = tile[k4 + 3][r2];
        *(s16x4*)(dst + (size_t)(nt * 32 + r2) * 256 + kt * 32 + k4) = v;
    }
}

// ---------------------------------------------------------------------------
// B-fragment loader: wave's 16 cols x full-K slice, fragment-layout-exact.
// ---------------------------------------------------------------------------
__device__ __forceinline__ void loadB(const ushort_t* __restrict__ WT, int c, s16x8 (&dst)[8]) {
    const int lane = threadIdx.x & 63, wave = threadIdx.x >> 6;
    const int lr = lane & 15, g8 = (lane >> 4) * 8;
    const ushort_t* bp = WT + (size_t)(c * 64 + wave * 16 + lr) * KD + g8;
#pragma unroll
    for (int kc = 0; kc < 8; ++kc) dst[kc] = *(const s16x8*)(bp + kc * 32);
}

// one gemm1 column-chunk: prefetch next B, 16 MFMA from LDS A, store.
// MODE 0: projb bf16. MODE 1: offb bf16 / logitb bf16.
template<int MODE>
__device__ __forceinline__ void g1step(
    int c, bool pre, const char* As, const ushort_t* __restrict__ WT,
    const float* __restrict__ bias, ushort_t* __restrict__ o_bf,
    ushort_t* __restrict__ o_lg, int bm, s16x8 (&cur)[8], s16x8 (&nxt)[8])
{
    const int lane = threadIdx.x & 63, wave = threadIdx.x >> 6;
    const int lr = lane & 15, g8 = (lane >> 4) * 8, rg = (lane >> 4) * 4;
    if (pre) loadB(WT, c + 1, nxt);
    f32x4 acc0 = (f32x4)0.f, acc1 = (f32x4)0.f;
#pragma unroll
    for (int kc = 0; kc < 8; ++kc) {
        const int kb = (kc * 32 + g8) * 2;
        s16x8 a0 = *(const s16x8*)(As + swz(lr,      kb));
        s16x8 a1 = *(const s16x8*)(As + swz(16 + lr, kb));
        acc0 = __builtin_amdgcn_mfma_f32_16x16x32_bf16(a0, cur[kc], acc0, 0, 0, 0);
        acc1 = __builtin_amdgcn_mfma_f32_16x16x32_bf16(a1, cur[kc], acc1, 0, 0, 0);
    }
    const int col = c * 64 + wave * 16 + lr;
    const float bv = bias[col];
#pragma unroll
    for (int mf = 0; mf < 2; ++mf) {
        const f32x4& a = mf ? acc1 : acc0;
#pragma unroll
        for (int rr = 0; rr < 4; ++rr) {
            const int row = bm + mf * 16 + rg + rr;
            if (row >= QTOT) continue;
            const float v = a[rr] + bv;
            if (MODE == 0) o_bf[(size_t)row * 256 + col] = f2b(v);
            else {
                if (col < 256) o_bf[(size_t)row * 256 + col] = f2b(v);
                else           o_lg[(size_t)row * 128 + col - 256] = f2b(v);
            }
        }
    }
}

// ---------------------------------------------------------------------------
// gemm1: 766 blocks; A-read-once (BM=32, full N per block), single barrier,
// B in registers double-buffered, logits out in bf16.
// ---------------------------------------------------------------------------
__global__ __launch_bounds__(256) void gemm1(
    const float* __restrict__ inflat, const float* __restrict__ query,
    const ushort_t* __restrict__ WvT, const ushort_t* __restrict__ WcT,
    const float* __restrict__ b_val, const float* __restrict__ bcomb,
    ushort_t* __restrict__ projb, ushort_t* __restrict__ offb,
    ushort_t* __restrict__ logitb)
{
    __shared__ char As[16384];
    const int b = blockIdx.x;
    const bool isval = b < 383;
    const int bm = (isval ? b : b - 383) * 32;
    const float* A = isval ? inflat : query;
    const ushort_t* WT = isval ? WvT : WcT;
    const int tid = threadIdx.x;

    s16x8 b0[8], b1[8];
    loadB(WT, 0, b0);                      // hides under A staging

    {   // stage A panel: 32 rows x 256 k, f32 -> bf16; linear coalesced map
        const float4* srcb = (const float4*)(A + (size_t)bm * KD);
        const int rem_rows = QTOT - bm;
#pragma unroll
        for (int j = 0; j < 8; ++j) {
            const int f4i = j * 256 + tid;
            const int row = f4i >> 6;
            const int colb = (f4i & 63) * 8;
            float4 f = make_float4(0.f, 0.f, 0.f, 0.f);
            if (row < rem_rows) f = srcb[f4i];
            s16x4 v;
            v[0] = f2b(f.x); v[1] = f2b(f.y); v[2] = f2b(f.z); v[3] = f2b(f.w);
            *(s16x4*)(As + swz(row, colb)) = v;
        }
    }
    __syncthreads();

    if (isval) {
        g1step<0>(0, true,  As, WT, b_val, projb, nullptr, bm, b0, b1);
        g1step<0>(1, true,  As, WT, b_val, projb, nullptr, bm, b1, b0);
        g1step<0>(2, true,  As, WT, b_val, projb, nullptr, bm, b0, b1);
        g1step<0>(3, false, As, WT, b_val, projb, nullptr, bm, b1, b0);
    } else {
        g1step<1>(0, true,  As, WT, bcomb, offb, logitb, bm, b0, b1);
        g1step<1>(1, true,  As, WT, bcomb, offb, logitb, bm, b1, b0);
        g1step<1>(2, true,  As, WT, bcomb, offb, logitb, bm, b0, b1);
        g1step<1>(3, true,  As, WT, bcomb, offb, logitb, bm, b1, b0);
        g1step<1>(4, true,  As, WT, bcomb, offb, logitb, bm, b0, b1);
        g1step<1>(5, false, As, WT, bcomb, offb, logitb, bm, b1, b0);
    }
}

// ---------------------------------------------------------------------------
// sample5: 4 queries/block, grid 3060; metadata->LDS, one barrier, 32
// independent 16B gathers/thread, levels sequential. Logits read as bf16.
// ---------------------------------------------------------------------------
__global__ __launch_bounds__(256) void sample5(
    const float* __restrict__ rp, const ushort_t* __restrict__ offb,
    const ushort_t* __restrict__ logitb, const ushort_t* __restrict__ projb,
    const int* __restrict__ sp, const int* __restrict__ lsi,
    ushort_t* __restrict__ outpre)
{
    const int q0 = blockIdx.x * 4;
    const int tid = threadIdx.x;

    __shared__ int   s_idx[512][4];
    __shared__ float s_w[512][4];

#pragma unroll
    for (int rep = 0; rep < 2; ++rep) {
        const int task = rep * 256 + tid;
        const int ql = task >> 7, t = task & 127;
        const int l = (t >> 2) & 3;
        const int q = q0 + ql;

        float logit = b2f(logitb[(size_t)q * 128 + t]);
        float mx = logit;
#pragma unroll
        for (int d = 1; d < 16; d <<= 1) mx = fmaxf(mx, __shfl_xor(mx, d));
        float e = __expf(logit - mx);
        float s = e;
#pragma unroll
        for (int d = 1; d < 16; d <<= 1) s += __shfl_xor(s, d);
        const float aw = e / s;

        const unsigned opk = *(const unsigned*)&offb[(size_t)q * 256 + t * 2];
        const float ox = __uint_as_float(opk << 16);
        const float oy = __uint_as_float(opk & 0xffff0000u);

        const int Hl = sp[l * 2], Wl = sp[l * 2 + 1], st = lsi[l];
        const float rx = rp[((size_t)q * 4 + l) * 2 + 0];
        const float ry = rp[((size_t)q * 4 + l) * 2 + 1];

        const float x = rx * (float)Wl + ox - 0.5f;
        const float y = ry * (float)Hl + oy - 0.5f;
        const float xf = floorf(x), yf = floorf(y);
        const int x0 = (int)xf, y0 = (int)yf;
        const float lx = x - xf, ly = y - yf;

        const bool vx0 = (x0 >= 0) && (x0 < Wl);
        const bool vx1 = (x0 + 1 >= 0) && (x0 + 1 < Wl);
        const bool vy0 = (y0 >= 0) && (y0 < Hl);
        const bool vy1 = (y0 + 1 >= 0) && (y0 + 1 < Hl);

        s_w[task][0] = (vx0 && vy0) ? aw * (1.f - ly) * (1.f - lx) : 0.f;
        s_w[task][1] = (vx1 && vy0) ? aw * (1.f - ly) * lx         : 0.f;
        s_w[task][2] = (vx0 && vy1) ? aw * ly * (1.f - lx)         : 0.f;
        s_w[task][3] = (vx1 && vy1) ? aw * ly * lx                 : 0.f;
        s_idx[task][0] = (vx0 && vy0) ? (st + y0 * Wl + x0) * 512           : 0;
        s_idx[task][1] = (vx1 && vy0) ? (st + y0 * Wl + x0 + 1) * 512       : 0;
        s_idx[task][2] = (vx0 && vy1) ? (st + (y0 + 1) * Wl + x0) * 512     : 0;
        s_idx[task][3] = (vx1 && vy1) ? (st + (y0 + 1) * Wl + x0 + 1) * 512 : 0;
    }
    __syncthreads();

    const int t = tid & 127, qlA = tid >> 7;
    const int h = t >> 4, pq = (t >> 2) & 3, c8 = t & 3;
    const char* basec = (const char*)projb + (h * 32 + c8 * 8) * 2;

    float aA[8] = {0,0,0,0,0,0,0,0};
    float aB[8] = {0,0,0,0,0,0,0,0};
#pragma unroll
    for (int l = 0; l < 4; ++l) {
        const int slotA = (qlA << 7)       + h * 16 + l * 4 + pq;
        const int slotB = ((qlA + 2) << 7) + h * 16 + l * 4 + pq;
        const int4   iA = *(const int4*)s_idx[slotA];
        const float4 wA = *(const float4*)s_w[slotA];
        const int4   iB = *(const int4*)s_idx[slotB];
        const float4 wB = *(const float4*)s_w[slotB];
#pragma unroll
        for (int c = 0; c < 4; ++c) {
            const int   idA = (c == 0) ? iA.x : (c == 1) ? iA.y : (c == 2) ? iA.z : iA.w;
            const float wwA = (c == 0) ? wA.x : (c == 1) ? wA.y : (c == 2) ? wA.z : wA.w;
            const uint4 v = *(const uint4*)(basec + idA);
            aA[0] += wwA * __uint_as_float(v.x << 16);
            aA[1] += wwA * __uint_as_float(v.x & 0xffff0000u);
            aA[2] += wwA * __uint_as_float(v.y << 16);
            aA[3] += wwA * __uint_as_float(v.y & 0xffff0000u);
            aA[4] += wwA * __uint_as_float(v.z << 16);
            aA[5] += wwA * __uint_as_float(v.z & 0xffff0000u);
            aA[6] += wwA * __uint_as_float(v.w << 16);
            aA[7] += wwA * __uint_as_float(v.w & 0xffff0000u);
        }
#pragma unroll
        for (int c = 0; c < 4; ++c) {
            const int   idB = (c == 0) ? iB.x : (c == 1) ? iB.y : (c == 2) ? iB.z : iB.w;
            const float wwB = (c == 0) ? wB.x : (c == 1) ? wB.y : (c == 2) ? wB.z : wB.w;
            const uint4 v = *(const uint4*)(basec + idB);
            aB[0] += wwB * __uint_as_float(v.x << 16);
            aB[1] += wwB * __uint_as_float(v.x & 0xffff0000u);
            aB[2] += wwB * __uint_as_float(v.y << 16);
            aB[3] += wwB * __uint_as_float(v.y & 0xffff0000u);
            aB[4] += wwB * __uint_as_float(v.z << 16);
            aB[5] += wwB * __uint_as_float(v.z & 0xffff0000u);
            aB[6] += wwB * __uint_as_float(v.w << 16);
            aB[7] += wwB * __uint_as_float(v.w & 0xffff0000u);
        }
    }
#pragma unroll
    for (int i = 0; i < 8; ++i) {
        aA[i] += __shfl_xor(aA[i], 4);  aA[i] += __shfl_xor(aA[i], 8);
        aB[i] += __shfl_xor(aB[i], 4);  aB[i] += __shfl_xor(aB[i], 8);
    }
    if (pq == 0) {
        const int colo = h * 32 + c8 * 8;
        uint4 o;
        o.x = (unsigned)f2b(aA[0]) | ((unsigned)f2b(aA[1]) << 16);
        o.y = (unsigned)f2b(aA[2]) | ((unsigned)f2b(aA[3]) << 16);
        o.z = (unsigned)f2b(aA[4]) | ((unsigned)f2b(aA[5]) << 16);
        o.w = (unsigned)f2b(aA[6]) | ((unsigned)f2b(aA[7]) << 16);
        *(uint4*)&outpre[(size_t)(q0 + qlA) * 256 + colo] = o;
        o.x = (unsigned)f2b(aB[0]) | ((unsigned)f2b(aB[1]) << 16);
        o.y = (unsigned)f2b(aB[2]) | ((unsigned)f2b(aB[3]) << 16);
        o.z = (unsigned)f2b(aB[4]) | ((unsigned)f2b(aB[5]) << 16);
        o.w = (unsigned)f2b(aB[6]) | ((unsigned)f2b(aB[7]) << 16);
        *(uint4*)&outpre[(size_t)(q0 + qlA + 2) * 256 + colo] = o;
    }
}

// ---------------------------------------------------------------------------
// gemm_o2: LDS-free, barrier-free. BM=16, grid 765 (12240 = 765*16 exact).
// A fragments loaded once; B double-buffered.
// ---------------------------------------------------------------------------
__global__ __launch_bounds__(256) void gemm_o2(
    const ushort_t* __restrict__ Ab, const ushort_t* __restrict__ WoT,
    const float* __restrict__ b_out, float* __restrict__ out)
{
    const int bm = blockIdx.x * 16;
    const int lane = threadIdx.x & 63, wave = threadIdx.x >> 6;
    const int lr = lane & 15, g8 = (lane >> 4) * 8, rg = (lane >> 4) * 4;

    s16x8 b0[8], b1[8];
    loadB(WoT, 0, b0);

    s16x8 af[8];
    {
        const ushort_t* ap = Ab + (size_t)(bm + lr) * KD + g8;
#pragma unroll
        for (int kc = 0; kc < 8; ++kc) af[kc] = *(const s16x8*)(ap + kc * 32);
    }

#pragma unroll
    for (int cc = 0; cc < 2; ++cc) {
        {   // chunk 2*cc with b0, prefetch into b1
            const int c = 2 * cc;
            loadB(WoT, c + 1, b1);
            f32x4 acc = (f32x4)0.f;
#pragma unroll
            for (int kc = 0; kc < 8; ++kc)
                acc = __builtin_amdgcn_mfma_f32_16x16x32_bf16(af[kc], b0[kc], acc, 0, 0, 0);
            const int col = c * 64 + wave * 16 + lr;
            const float bv = b_out[col];
#pragma unroll
            for (int rr = 0; rr < 4; ++rr)
                out[(size_t)(bm + rg + rr) * 256 + col] = acc[rr] + bv;
        }
        {   // chunk 2*cc+1 with b1, prefetch into b0
            const int c = 2 * cc + 1;
            if (c + 1 < 4) loadB(WoT, c + 1, b0);
            f32x4 acc = (f32x4)0.f;
#pragma unroll
            for (int kc = 0; kc < 8; ++kc)
                acc = __builtin_amdgcn_mfma_f32_16x16x32_bf16(af[kc], b1[kc], acc, 0, 0, 0);
            const int col = c * 64 + wave * 16 + lr;
            const float bv = b_out[col];
#pragma unroll
            for (int rr = 0; rr < 4; ++rr)
                out[(size_t)(bm + rg + rr) * 256 + col] = acc[rr] + bv;
        }
    }
}

// ---------------------------------------------------------------------------
extern "C" void kernel_launch(void* const* d_in, const int* in_sizes, int n_in,
                              void* d_out, int out_size, void* d_ws, size_t ws_size,
                              hipStream_t stream) {
    const float* query  = (const float*)d_in[0];
    const float* rp     = (const float*)d_in[1];
    const float* inflat = (const float*)d_in[2];
    const int*   sp     = (const int*)d_in[3];
    const int*   lsi    = (const int*)d_in[4];
    const float* W_off  = (const float*)d_in[5];
    const float* b_off  = (const float*)d_in[6];
    const float* W_attn = (const float*)d_in[7];
    const float* b_attn = (const float*)d_in[8];
    const float* W_val  = (const float*)d_in[9];
    const float* b_val  = (const float*)d_in[10];
    const float* W_out  = (const float*)d_in[11];
    const float* b_out  = (const float*)d_in[12];
    float* out = (float*)d_out;

    char* ws = (char*)d_ws;
    ushort_t* projb  = (ushort_t*)ws; ws += (size_t)QTOT * 256 * 2;
    ushort_t* offb   = (ushort_t*)ws; ws += (size_t)QTOT * 256 * 2;
    ushort_t* logitb = (ushort_t*)ws; ws += (size_t)QTOT * 128 * 2;
    ushort_t* outpre = (ushort_t*)ws; ws += (size_t)QTOT * 256 * 2;
    ushort_t* WvT    = (ushort_t*)ws; ws += 65536 * 2;
    ushort_t* WcT    = (ushort_t*)ws; ws += 98304 * 2;
    ushort_t* WoT    = (ushort_t*)ws; ws += 65536 * 2;
    float*    bcomb  = (float*)ws;    ws += 384 * 4;

    prep2<<<dim3(225), dim3(256), 0, stream>>>(W_val, W_off, W_attn, W_out, b_off, b_attn,
                                               WvT, WcT, WoT, bcomb);

    gemm1<<<dim3(766), dim3(256), 0, stream>>>(inflat, query, WvT, WcT, b_val, bcomb,
                                               projb, offb, logitb);

    sample5<<<dim3(3060), dim3(256), 0, stream>>>(rp, offb, logitb, projb, sp, lsi, outpre);

    gemm_o2<<<dim3(765), dim3(256), 0, stream>>>(outpre, WoT, b_out, out);
}

// Round 11
// 69.505 us; speedup vs baseline: 1.1842x; 1.1842x over previous
//
#include <hip/hip_runtime.h>

#define QTOT 12240
#define KD   256

typedef float f32x4 __attribute__((ext_vector_type(4)));
typedef short s16x8 __attribute__((ext_vector_type(8)));
typedef short s16x4 __attribute__((ext_vector_type(4)));
typedef unsigned short ushort_t;

__device__ __forceinline__ unsigned short f2b(float x) {
    union { float f; unsigned u; } c; c.f = x;
    unsigned r = c.u + 0x7fffu + ((c.u >> 16) & 1u);
    return (unsigned short)(r >> 16);
}
// LDS row: 512B, XOR bits 4-6 of k-byte with row&7 (write & read sides).
// Low 4 bits of kb pass through, so 8B-aligned kb works too.
__device__ __forceinline__ int swz(int row, int kb) { return row * 512 + (kb ^ ((row & 7) << 4)); }

// ---------------------------------------------------------------------------
// prep: weight transpose+bf16, combined off/attn bias (verified)
// ---------------------------------------------------------------------------
__global__ __launch_bounds__(256) void prep(
    const float* __restrict__ W_val, const float* __restrict__ W_off,
    const float* __restrict__ W_attn, const float* __restrict__ W_out,
    const float* __restrict__ b_off, const float* __restrict__ b_attn,
    ushort_t* __restrict__ WvT, ushort_t* __restrict__ WcT,
    ushort_t* __restrict__ WoT, float* __restrict__ bcomb)
{
    int id = blockIdx.x * 256 + threadIdx.x;
    if (id < 65536) { int n = id >> 8, k = id & 255; WvT[id] = f2b(W_val[k * 256 + n]); }
    else if (id < 163840) {
        int t = id - 65536; int n = t >> 8, k = t & 255;
        float v = (n < 256) ? W_off[k * 256 + n] : W_attn[k * 128 + (n - 256)];
        WcT[t] = f2b(v);
    } else if (id < 229376) {
        int t = id - 163840; int n = t >> 8, k = t & 255;
        WoT[t] = f2b(W_out[k * 256 + n]);
    } else if (id < 229760) {
        int t = id - 229376; bcomb[t] = (t < 256) ? b_off[t] : b_attn[t - 256];
    }
}

// ---------------------------------------------------------------------------
// gemm1: R7 structure (A-read-once, B-in-registers, 1 barrier) with a
// fully-coalesced A-stage: per load inst a wave reads 1KB contiguous
// (lane-consecutive float4, wave-uniform row), LDS write is contiguous b64.
// ---------------------------------------------------------------------------
__global__ __launch_bounds__(256) void gemm1(
    const float* __restrict__ inflat, const float* __restrict__ query,
    const ushort_t* __restrict__ WvT, const ushort_t* __restrict__ WcT,
    const float* __restrict__ b_val, const float* __restrict__ bcomb,
    ushort_t* __restrict__ projb, ushort_t* __restrict__ offb,
    float* __restrict__ logitf)
{
    __shared__ char As[16384];
    const int b = blockIdx.x;
    const bool isval = b < 383;
    const int bm = (isval ? b : b - 383) * 32;
    const float* A = isval ? inflat : query;
    const ushort_t* WT = isval ? WvT : WcT;
    const int nc = isval ? 4 : 6;

    const int tid = threadIdx.x, lane = tid & 63, wave = tid >> 6;
    const int lr = lane & 15, g8 = (lane >> 4) * 8;

    {   // stage A panel: 32 rows x 256 k, f32 -> bf16; linear coalesced map
        const float4* srcb = (const float4*)(A + (size_t)bm * KD);
        const int rem_rows = QTOT - bm;
#pragma unroll
        for (int j = 0; j < 8; ++j) {
            const int f4i = j * 256 + tid;
            const int row = f4i >> 6;                 // wave-uniform
            const int colb = (f4i & 63) * 8;          // bf16 byte offset in row
            float4 f = make_float4(0.f, 0.f, 0.f, 0.f);
            if (row < rem_rows) f = srcb[f4i];
            s16x4 v;
            v[0] = f2b(f.x); v[1] = f2b(f.y); v[2] = f2b(f.z); v[3] = f2b(f.w);
            *(s16x4*)(As + swz(row, colb)) = v;
        }
    }
    __syncthreads();

    const int rg = (lane >> 4) * 4;

    for (int c = 0; c < nc; ++c) {
        const int col = c * 64 + wave * 16 + lr;
        s16x8 bfr[8];
        {
            const ushort_t* bp = WT + (size_t)col * KD + g8;
#pragma unroll
            for (int kc = 0; kc < 8; ++kc) bfr[kc] = *(const s16x8*)(bp + kc * 32);
        }
        f32x4 acc[2];
        acc[0] = (f32x4)0.f; acc[1] = (f32x4)0.f;
#pragma unroll
        for (int kc = 0; kc < 8; ++kc) {
            const int kb = (kc * 32 + g8) * 2;
            s16x8 a0 = *(const s16x8*)(As + swz(lr,      kb));
            s16x8 a1 = *(const s16x8*)(As + swz(16 + lr, kb));
            acc[0] = __builtin_amdgcn_mfma_f32_16x16x32_bf16(a0, bfr[kc], acc[0], 0, 0, 0);
            acc[1] = __builtin_amdgcn_mfma_f32_16x16x32_bf16(a1, bfr[kc], acc[1], 0, 0, 0);
        }
        const float bb = isval ? b_val[col] : bcomb[col];
#pragma unroll
        for (int mf = 0; mf < 2; ++mf)
#pragma unroll
            for (int rr = 0; rr < 4; ++rr) {
                const int row = bm + mf * 16 + rg + rr;
                if (row >= QTOT) continue;
                const float v = acc[mf][rr] + bb;
                if (isval)          projb[(size_t)row * 256 + col] = f2b(v);
                else if (col < 256) offb [(size_t)row * 256 + col] = f2b(v);
                else                logitf[(size_t)row * 128 + col - 256] = v;
            }
    }
}

// ---------------------------------------------------------------------------
// sample5: 4 queries/block, 256 threads, grid 3060. Metadata for 512 slots
// (2 reps), one barrier, then 2 gather tasks/thread = 32 independent 16B
// loads in flight. Levels iterated sequentially. 16KB LDS.
// ---------------------------------------------------------------------------
__global__ __launch_bounds__(256) void sample5(
    const float* __restrict__ rp, const ushort_t* __restrict__ offb,
    const float* __restrict__ logitf, const ushort_t* __restrict__ projb,
    const int* __restrict__ sp, const int* __restrict__ lsi,
    ushort_t* __restrict__ outpre)
{
    const int q0 = blockIdx.x * 4;
    const int tid = threadIdx.x;

    __shared__ int   s_idx[512][4];
    __shared__ float s_w[512][4];

#pragma unroll
    for (int rep = 0; rep < 2; ++rep) {
        const int task = rep * 256 + tid;
        const int ql = task >> 7, t = task & 127;
        const int l = (t >> 2) & 3;
        const int q = q0 + ql;

        float logit = logitf[(size_t)q * 128 + t];
        float mx = logit;
#pragma unroll
        for (int d = 1; d < 16; d <<= 1) mx = fmaxf(mx, __shfl_xor(mx, d));
        float e = __expf(logit - mx);
        float s = e;
#pragma unroll
        for (int d = 1; d < 16; d <<= 1) s += __shfl_xor(s, d);
        const float aw = e / s;

        const unsigned opk = *(const unsigned*)&offb[(size_t)q * 256 + t * 2];
        const float ox = __uint_as_float(opk << 16);
        const float oy = __uint_as_float(opk & 0xffff0000u);

        const int Hl = sp[l * 2], Wl = sp[l * 2 + 1], st = lsi[l];
        const float rx = rp[((size_t)q * 4 + l) * 2 + 0];
        const float ry = rp[((size_t)q * 4 + l) * 2 + 1];

        const float x = rx * (float)Wl + ox - 0.5f;
        const float y = ry * (float)Hl + oy - 0.5f;
        const float xf = floorf(x), yf = floorf(y);
        const int x0 = (int)xf, y0 = (int)yf;
        const float lx = x - xf, ly = y - yf;

        const bool vx0 = (x0 >= 0) && (x0 < Wl);
        const bool vx1 = (x0 + 1 >= 0) && (x0 + 1 < Wl);
        const bool vy0 = (y0 >= 0) && (y0 < Hl);
        const bool vy1 = (y0 + 1 >= 0) && (y0 + 1 < Hl);

        s_w[task][0] = (vx0 && vy0) ? aw * (1.f - ly) * (1.f - lx) : 0.f;
        s_w[task][1] = (vx1 && vy0) ? aw * (1.f - ly) * lx         : 0.f;
        s_w[task][2] = (vx0 && vy1) ? aw * ly * (1.f - lx)         : 0.f;
        s_w[task][3] = (vx1 && vy1) ? aw * ly * lx                 : 0.f;
        s_idx[task][0] = (vx0 && vy0) ? (st + y0 * Wl + x0) * 512           : 0;
        s_idx[task][1] = (vx1 && vy0) ? (st + y0 * Wl + x0 + 1) * 512       : 0;
        s_idx[task][2] = (vx0 && vy1) ? (st + (y0 + 1) * Wl + x0) * 512     : 0;
        s_idx[task][3] = (vx1 && vy1) ? (st + (y0 + 1) * Wl + x0 + 1) * 512 : 0;
    }
    __syncthreads();

    const int t = tid & 127, qlA = tid >> 7;            // qlA in {0,1}
    const int h = t >> 4, pq = (t >> 2) & 3, c8 = t & 3;
    const char* basec = (const char*)projb + (h * 32 + c8 * 8) * 2;

    float aA[8] = {0,0,0,0,0,0,0,0};
    float aB[8] = {0,0,0,0,0,0,0,0};
#pragma unroll
    for (int l = 0; l < 4; ++l) {
        const int slotA = (qlA << 7)       + h * 16 + l * 4 + pq;
        const int slotB = ((qlA + 2) << 7) + h * 16 + l * 4 + pq;
        const int4   iA = *(const int4*)s_idx[slotA];
        const float4 wA = *(const float4*)s_w[slotA];
        const int4   iB = *(const int4*)s_idx[slotB];
        const float4 wB = *(const float4*)s_w[slotB];
#pragma unroll
        for (int c = 0; c < 4; ++c) {
            const int   idA = (c == 0) ? iA.x : (c == 1) ? iA.y : (c == 2) ? iA.z : iA.w;
            const float wwA = (c == 0) ? wA.x : (c == 1) ? wA.y : (c == 2) ? wA.z : wA.w;
            const uint4 v = *(const uint4*)(basec + idA);
            aA[0] += wwA * __uint_as_float(v.x << 16);
            aA[1] += wwA * __uint_as_float(v.x & 0xffff0000u);
            aA[2] += wwA * __uint_as_float(v.y << 16);
            aA[3] += wwA * __uint_as_float(v.y & 0xffff0000u);
            aA[4] += wwA * __uint_as_float(v.z << 16);
            aA[5] += wwA * __uint_as_float(v.z & 0xffff0000u);
            aA[6] += wwA * __uint_as_float(v.w << 16);
            aA[7] += wwA * __uint_as_float(v.w & 0xffff0000u);
        }
#pragma unroll
        for (int c = 0; c < 4; ++c) {
            const int   idB = (c == 0) ? iB.x : (c == 1) ? iB.y : (c == 2) ? iB.z : iB.w;
            const float wwB = (c == 0) ? wB.x : (c == 1) ? wB.y : (c == 2) ? wB.z : wB.w;
            const uint4 v = *(const uint4*)(basec + idB);
            aB[0] += wwB * __uint_as_float(v.x << 16);
            aB[1] += wwB * __uint_as_float(v.x & 0xffff0000u);
            aB[2] += wwB * __uint_as_float(v.y << 16);
            aB[3] += wwB * __uint_as_float(v.y & 0xffff0000u);
            aB[4] += wwB * __uint_as_float(v.z << 16);
            aB[5] += wwB * __uint_as_float(v.z & 0xffff0000u);
            aB[6] += wwB * __uint_as_float(v.w << 16);
            aB[7] += wwB * __uint_as_float(v.w & 0xffff0000u);
        }
    }
#pragma unroll
    for (int i = 0; i < 8; ++i) {
        aA[i] += __shfl_xor(aA[i], 4);  aA[i] += __shfl_xor(aA[i], 8);
        aB[i] += __shfl_xor(aB[i], 4);  aB[i] += __shfl_xor(aB[i], 8);
    }
    if (pq == 0) {
        const int colo = h * 32 + c8 * 8;
        uint4 o;
        o.x = (unsigned)f2b(aA[0]) | ((unsigned)f2b(aA[1]) << 16);
        o.y = (unsigned)f2b(aA[2]) | ((unsigned)f2b(aA[3]) << 16);
        o.z = (unsigned)f2b(aA[4]) | ((unsigned)f2b(aA[5]) << 16);
        o.w = (unsigned)f2b(aA[6]) | ((unsigned)f2b(aA[7]) << 16);
        *(uint4*)&outpre[(size_t)(q0 + qlA) * 256 + colo] = o;
        o.x = (unsigned)f2b(aB[0]) | ((unsigned)f2b(aB[1]) << 16);
        o.y = (unsigned)f2b(aB[2]) | ((unsigned)f2b(aB[3]) << 16);
        o.z = (unsigned)f2b(aB[4]) | ((unsigned)f2b(aB[5]) << 16);
        o.w = (unsigned)f2b(aB[6]) | ((unsigned)f2b(aB[7]) << 16);
        *(uint4*)&outpre[(size_t)(q0 + qlA + 2) * 256 + colo] = o;
    }
}

// ---------------------------------------------------------------------------
// gemm_o: LDS-free, barrier-free (verified R7). 383 blocks, BM=32, N=256.
// ---------------------------------------------------------------------------
__global__ __launch_bounds__(256) void gemm_o(
    const ushort_t* __restrict__ Ab, const ushort_t* __restrict__ WoT,
    const float* __restrict__ b_out, float* __restrict__ out)
{
    const int bm = blockIdx.x * 32;
    const int tid = threadIdx.x, lane = tid & 63, wave = tid >> 6;
    const int lr = lane & 15, g8 = (lane >> 4) * 8;
    const int rg = (lane >> 4) * 4;

    const ushort_t* ap0;
    const ushort_t* ap1;
    {
        int r0 = bm + lr;      if (r0 >= QTOT) r0 = QTOT - 1;
        int r1 = bm + 16 + lr; if (r1 >= QTOT) r1 = QTOT - 1;
        ap0 = Ab + (size_t)r0 * KD + g8;
        ap1 = Ab + (size_t)r1 * KD + g8;
    }

#pragma unroll
    for (int c = 0; c < 4; ++c) {
        const int col = c * 64 + wave * 16 + lr;
        s16x8 bfr[8];
        {
            const ushort_t* bp = WoT + (size_t)col * KD + g8;
#pragma unroll
            for (int kc = 0; kc < 8; ++kc) bfr[kc] = *(const s16x8*)(bp + kc * 32);
        }
        f32x4 acc[2];
        acc[0] = (f32x4)0.f; acc[1] = (f32x4)0.f;
#pragma unroll
        for (int kc = 0; kc < 8; ++kc) {
            s16x8 a0 = *(const s16x8*)(ap0 + kc * 32);
            s16x8 a1 = *(const s16x8*)(ap1 + kc * 32);
            acc[0] = __builtin_amdgcn_mfma_f32_16x16x32_bf16(a0, bfr[kc], acc[0], 0, 0, 0);
            acc[1] = __builtin_amdgcn_mfma_f32_16x16x32_bf16(a1, bfr[kc], acc[1], 0, 0, 0);
        }
        const float bb = b_out[col];
#pragma unroll
        for (int mf = 0; mf < 2; ++mf)
#pragma unroll
            for (int rr = 0; rr < 4; ++rr) {
                const int row = bm + mf * 16 + rg + rr;
                if (row < QTOT) out[(size_t)row * 256 + col] = acc[mf][rr] + bb;
            }
    }
}

// ---------------------------------------------------------------------------
extern "C" void kernel_launch(void* const* d_in, const int* in_sizes, int n_in,
                              void* d_out, int out_size, void* d_ws, size_t ws_size,
                              hipStream_t stream) {
    const float* query  = (const float*)d_in[0];
    const float* rp     = (const float*)d_in[1];
    const float* inflat = (const float*)d_in[2];
    const int*   sp     = (const int*)d_in[3];
    const int*   lsi    = (const int*)d_in[4];
    const float* W_off  = (const float*)d_in[5];
    const float* b_off  = (const float*)d_in[6];
    const float* W_attn = (const float*)d_in[7];
    const float* b_attn = (const float*)d_in[8];
    const float* W_val  = (const float*)d_in[9];
    const float* b_val  = (const float*)d_in[10];
    const float* W_out  = (const float*)d_in[11];
    const float* b_out  = (const float*)d_in[12];
    float* out = (float*)d_out;

    char* ws = (char*)d_ws;
    ushort_t* projb  = (ushort_t*)ws; ws += (size_t)QTOT * 256 * 2;
    ushort_t* offb   = (ushort_t*)ws; ws += (size_t)QTOT * 256 * 2;
    float*    logitf = (float*)ws;    ws += (size_t)QTOT * 128 * 4;
    ushort_t* outpre = (ushort_t*)ws; ws += (size_t)QTOT * 256 * 2;
    ushort_t* WvT    = (ushort_t*)ws; ws += 65536 * 2;
    ushort_t* WcT    = (ushort_t*)ws; ws += 98304 * 2;
    ushort_t* WoT    = (ushort_t*)ws; ws += 65536 * 2;
    float*    bcomb  = (float*)ws;    ws += 384 * 4;

    prep<<<dim3(898), dim3(256), 0, stream>>>(W_val, W_off, W_attn, W_out, b_off, b_attn,
                                              WvT, WcT, WoT, bcomb);

    gemm1<<<dim3(766), dim3(256), 0, stream>>>(inflat, query, WvT, WcT, b_val, bcomb,
                                               projb, offb, logitf);

    sample5<<<dim3(3060), dim3(256), 0, stream>>>(rp, offb, logitf, projb, sp, lsi, outpre);

    gemm_o<<<dim3(383), dim3(256), 0, stream>>>(outpre, WoT, b_out, out);
}

// Round 12
// 68.927 us; speedup vs baseline: 1.1942x; 1.0084x over previous
//
#include <hip/hip_runtime.h>

#define QTOT 12240
#define KD   256

typedef float f32x4 __attribute__((ext_vector_type(4)));
typedef short s16x8 __attribute__((ext_vector_type(8)));
typedef short s16x4 __attribute__((ext_vector_type(4)));
typedef unsigned short ushort_t;

__device__ __forceinline__ unsigned short f2b(float x) {
    union { float f; unsigned u; } c; c.f = x;
    unsigned r = c.u + 0x7fffu + ((c.u >> 16) & 1u);
    return (unsigned short)(r >> 16);
}
// LDS row: 512B, XOR bits 4-6 of k-byte with row&7 (write & read sides).
__device__ __forceinline__ int swz(int row, int kb) { return row * 512 + (kb ^ ((row & 7) << 4)); }

// ---------------------------------------------------------------------------
// prep: weight transpose+bf16, combined off/attn bias (verified)
// ---------------------------------------------------------------------------
__global__ __launch_bounds__(256) void prep(
    const float* __restrict__ W_val, const float* __restrict__ W_off,
    const float* __restrict__ W_attn, const float* __restrict__ W_out,
    const float* __restrict__ b_off, const float* __restrict__ b_attn,
    ushort_t* __restrict__ WvT, ushort_t* __restrict__ WcT,
    ushort_t* __restrict__ WoT, float* __restrict__ bcomb)
{
    int id = blockIdx.x * 256 + threadIdx.x;
    if (id < 65536) { int n = id >> 8, k = id & 255; WvT[id] = f2b(W_val[k * 256 + n]); }
    else if (id < 163840) {
        int t = id - 65536; int n = t >> 8, k = t & 255;
        float v = (n < 256) ? W_off[k * 256 + n] : W_attn[k * 128 + (n - 256)];
        WcT[t] = f2b(v);
    } else if (id < 229376) {
        int t = id - 163840; int n = t >> 8, k = t & 255;
        WoT[t] = f2b(W_out[k * 256 + n]);
    } else if (id < 229760) {
        int t = id - 229376; bcomb[t] = (t < 256) ? b_off[t] : b_attn[t - 256];
    }
}

// ---------------------------------------------------------------------------
// gemm1: unchanged champion (A-read-once, B-in-registers, 1 barrier).
// ---------------------------------------------------------------------------
__global__ __launch_bounds__(256) void gemm1(
    const float* __restrict__ inflat, const float* __restrict__ query,
    const ushort_t* __restrict__ WvT, const ushort_t* __restrict__ WcT,
    const float* __restrict__ b_val, const float* __restrict__ bcomb,
    ushort_t* __restrict__ projb, ushort_t* __restrict__ offb,
    float* __restrict__ logitf)
{
    __shared__ char As[16384];
    const int b = blockIdx.x;
    const bool isval = b < 383;
    const int bm = (isval ? b : b - 383) * 32;
    const float* A = isval ? inflat : query;
    const ushort_t* WT = isval ? WvT : WcT;
    const int nc = isval ? 4 : 6;

    const int tid = threadIdx.x, lane = tid & 63, wave = tid >> 6;
    const int lr = lane & 15, g8 = (lane >> 4) * 8;

    {   // stage A panel: 32 rows x 256 k, f32 -> bf16; linear coalesced map
        const float4* srcb = (const float4*)(A + (size_t)bm * KD);
        const int rem_rows = QTOT - bm;
#pragma unroll
        for (int j = 0; j < 8; ++j) {
            const int f4i = j * 256 + tid;
            const int row = f4i >> 6;
            const int colb = (f4i & 63) * 8;
            float4 f = make_float4(0.f, 0.f, 0.f, 0.f);
            if (row < rem_rows) f = srcb[f4i];
            s16x4 v;
            v[0] = f2b(f.x); v[1] = f2b(f.y); v[2] = f2b(f.z); v[3] = f2b(f.w);
            *(s16x4*)(As + swz(row, colb)) = v;
        }
    }
    __syncthreads();

    const int rg = (lane >> 4) * 4;

    for (int c = 0; c < nc; ++c) {
        const int col = c * 64 + wave * 16 + lr;
        s16x8 bfr[8];
        {
            const ushort_t* bp = WT + (size_t)col * KD + g8;
#pragma unroll
            for (int kc = 0; kc < 8; ++kc) bfr[kc] = *(const s16x8*)(bp + kc * 32);
        }
        f32x4 acc[2];
        acc[0] = (f32x4)0.f; acc[1] = (f32x4)0.f;
#pragma unroll
        for (int kc = 0; kc < 8; ++kc) {
            const int kb = (kc * 32 + g8) * 2;
            s16x8 a0 = *(const s16x8*)(As + swz(lr,      kb));
            s16x8 a1 = *(const s16x8*)(As + swz(16 + lr, kb));
            acc[0] = __builtin_amdgcn_mfma_f32_16x16x32_bf16(a0, bfr[kc], acc[0], 0, 0, 0);
            acc[1] = __builtin_amdgcn_mfma_f32_16x16x32_bf16(a1, bfr[kc], acc[1], 0, 0, 0);
        }
        const float bb = isval ? b_val[col] : bcomb[col];
#pragma unroll
        for (int mf = 0; mf < 2; ++mf)
#pragma unroll
            for (int rr = 0; rr < 4; ++rr) {
                const int row = bm + mf * 16 + rg + rr;
                if (row >= QTOT) continue;
                const float v = acc[mf][rr] + bb;
                if (isval)          projb[(size_t)row * 256 + col] = f2b(v);
                else if (col < 256) offb [(size_t)row * 256 + col] = f2b(v);
                else                logitf[(size_t)row * 128 + col - 256] = v;
            }
    }
}

// ---------------------------------------------------------------------------
// sample6: head-half split for L2 residency. Grid 3060 = 1530 q-groups x 2
// head-halves (hh slow index -> GPU processes heads 0-3 then 4-7; each
// half's gather working set = 3.15MB < 4MB L2/XCD). Block = 8 queries x
// 4 heads, 256 threads, 16KB LDS, 32 gathers/thread, 1 shfl reduce level.
// ---------------------------------------------------------------------------
__global__ __launch_bounds__(256) void sample6(
    const float* __restrict__ rp, const ushort_t* __restrict__ offb,
    const float* __restrict__ logitf, const ushort_t* __restrict__ projb,
    const int* __restrict__ sp, const int* __restrict__ lsi,
    ushort_t* __restrict__ outpre)
{
    const int bid = blockIdx.x;
    const int hh = (bid >= 1530) ? 1 : 0;       // head-half (slow index)
    const int g  = hh ? (bid - 1530) : bid;     // query group
    const int q0 = g * 8;
    const int tid = threadIdx.x;

    __shared__ int   s_idx[512][4];
    __shared__ float s_w[512][4];

    // ---- metadata: 512 tasks = (ql 0..7, h' 0..3, l 0..3, p 0..3) ----
#pragma unroll
    for (int rep = 0; rep < 2; ++rep) {
        const int task = rep * 256 + tid;
        const int ql = task >> 6;
        const int hp = (task >> 4) & 3;         // head within half
        const int lp = task & 15;
        const int l = lp >> 2;
        const int q = q0 + ql;
        const int gh = hh * 4 + hp;             // global head
        const int t128 = gh * 16 + lp;          // slot within query's 128

        float logit = logitf[(size_t)q * 128 + t128];
        float mx = logit;
#pragma unroll
        for (int d = 1; d < 16; d <<= 1) mx = fmaxf(mx, __shfl_xor(mx, d));
        float e = __expf(logit - mx);
        float s = e;
#pragma unroll
        for (int d = 1; d < 16; d <<= 1) s += __shfl_xor(s, d);
        const float aw = e / s;

        const unsigned opk = *(const unsigned*)&offb[(size_t)q * 256 + t128 * 2];
        const float ox = __uint_as_float(opk << 16);
        const float oy = __uint_as_float(opk & 0xffff0000u);

        const int Hl = sp[l * 2], Wl = sp[l * 2 + 1], st = lsi[l];
        const float rx = rp[((size_t)q * 4 + l) * 2 + 0];
        const float ry = rp[((size_t)q * 4 + l) * 2 + 1];

        const float x = rx * (float)Wl + ox - 0.5f;
        const float y = ry * (float)Hl + oy - 0.5f;
        const float xf = floorf(x), yf = floorf(y);
        const int x0 = (int)xf, y0 = (int)yf;
        const float lx = x - xf, ly = y - yf;

        const bool vx0 = (x0 >= 0) && (x0 < Wl);
        const bool vx1 = (x0 + 1 >= 0) && (x0 + 1 < Wl);
        const bool vy0 = (y0 >= 0) && (y0 < Hl);
        const bool vy1 = (y0 + 1 >= 0) && (y0 + 1 < Hl);

        s_w[task][0] = (vx0 && vy0) ? aw * (1.f - ly) * (1.f - lx) : 0.f;
        s_w[task][1] = (vx1 && vy0) ? aw * (1.f - ly) * lx         : 0.f;
        s_w[task][2] = (vx0 && vy1) ? aw * ly * (1.f - lx)         : 0.f;
        s_w[task][3] = (vx1 && vy1) ? aw * ly * lx                 : 0.f;
        s_idx[task][0] = (vx0 && vy0) ? (st + y0 * Wl + x0) * 512           : 0;
        s_idx[task][1] = (vx1 && vy0) ? (st + y0 * Wl + x0 + 1) * 512       : 0;
        s_idx[task][2] = (vx0 && vy1) ? (st + (y0 + 1) * Wl + x0) * 512     : 0;
        s_idx[task][3] = (vx1 && vy1) ? (st + (y0 + 1) * Wl + x0 + 1) * 512 : 0;
    }
    __syncthreads();

    // ---- gathers: thread = (ql 0..7, h' 0..3, pq 0..1, c8 0..3) ----
    const int c8 = tid & 3;
    const int pq = (tid >> 2) & 1;
    const int hp = (tid >> 3) & 3;
    const int ql = tid >> 5;
    const int gh = hh * 4 + hp;
    const char* basec = (const char*)projb + (gh * 32 + c8 * 8) * 2;
    const int slot0 = (ql << 6) | (hp << 4);

    float a0 = 0, a1 = 0, a2 = 0, a3 = 0, a4 = 0, a5 = 0, a6 = 0, a7 = 0;
#pragma unroll
    for (int l = 0; l < 4; ++l) {
#pragma unroll
        for (int j = 0; j < 2; ++j) {
            const int slot = slot0 | (l << 2) | (pq * 2 + j);
            const int4   i4 = *(const int4*)s_idx[slot];
            const float4 w4 = *(const float4*)s_w[slot];
#pragma unroll
            for (int c = 0; c < 4; ++c) {
                const int   id = (c == 0) ? i4.x : (c == 1) ? i4.y : (c == 2) ? i4.z : i4.w;
                const float w  = (c == 0) ? w4.x : (c == 1) ? w4.y : (c == 2) ? w4.z : w4.w;
                const uint4 v = *(const uint4*)(basec + id);
                a0 += w * __uint_as_float(v.x << 16);
                a1 += w * __uint_as_float(v.x & 0xffff0000u);
                a2 += w * __uint_as_float(v.y << 16);
                a3 += w * __uint_as_float(v.y & 0xffff0000u);
                a4 += w * __uint_as_float(v.z << 16);
                a5 += w * __uint_as_float(v.z & 0xffff0000u);
                a6 += w * __uint_as_float(v.w << 16);
                a7 += w * __uint_as_float(v.w & 0xffff0000u);
            }
        }
    }
    a0 += __shfl_xor(a0, 4); a1 += __shfl_xor(a1, 4);
    a2 += __shfl_xor(a2, 4); a3 += __shfl_xor(a3, 4);
    a4 += __shfl_xor(a4, 4); a5 += __shfl_xor(a5, 4);
    a6 += __shfl_xor(a6, 4); a7 += __shfl_xor(a7, 4);

    if (pq == 0) {
        uint4 o;
        o.x = (unsigned)f2b(a0) | ((unsigned)f2b(a1) << 16);
        o.y = (unsigned)f2b(a2) | ((unsigned)f2b(a3) << 16);
        o.z = (unsigned)f2b(a4) | ((unsigned)f2b(a5) << 16);
        o.w = (unsigned)f2b(a6) | ((unsigned)f2b(a7) << 16);
        *(uint4*)&outpre[(size_t)(q0 + ql) * 256 + gh * 32 + c8 * 8] = o;
    }
}

// ---------------------------------------------------------------------------
// gemm_o: unchanged champion (LDS-free, barrier-free, BM=32, N=256).
// ---------------------------------------------------------------------------
__global__ __launch_bounds__(256) void gemm_o(
    const ushort_t* __restrict__ Ab, const ushort_t* __restrict__ WoT,
    const float* __restrict__ b_out, float* __restrict__ out)
{
    const int bm = blockIdx.x * 32;
    const int tid = threadIdx.x, lane = tid & 63, wave = tid >> 6;
    const int lr = lane & 15, g8 = (lane >> 4) * 8;
    const int rg = (lane >> 4) * 4;

    const ushort_t* ap0;
    const ushort_t* ap1;
    {
        int r0 = bm + lr;      if (r0 >= QTOT) r0 = QTOT - 1;
        int r1 = bm + 16 + lr; if (r1 >= QTOT) r1 = QTOT - 1;
        ap0 = Ab + (size_t)r0 * KD + g8;
        ap1 = Ab + (size_t)r1 * KD + g8;
    }

#pragma unroll
    for (int c = 0; c < 4; ++c) {
        const int col = c * 64 + wave * 16 + lr;
        s16x8 bfr[8];
        {
            const ushort_t* bp = WoT + (size_t)col * KD + g8;
#pragma unroll
            for (int kc = 0; kc < 8; ++kc) bfr[kc] = *(const s16x8*)(bp + kc * 32);
        }
        f32x4 acc[2];
        acc[0] = (f32x4)0.f; acc[1] = (f32x4)0.f;
#pragma unroll
        for (int kc = 0; kc < 8; ++kc) {
            s16x8 a0 = *(const s16x8*)(ap0 + kc * 32);
            s16x8 a1 = *(const s16x8*)(ap1 + kc * 32);
            acc[0] = __builtin_amdgcn_mfma_f32_16x16x32_bf16(a0, bfr[kc], acc[0], 0, 0, 0);
            acc[1] = __builtin_amdgcn_mfma_f32_16x16x32_bf16(a1, bfr[kc], acc[1], 0, 0, 0);
        }
        const float bb = b_out[col];
#pragma unroll
        for (int mf = 0; mf < 2; ++mf)
#pragma unroll
            for (int rr = 0; rr < 4; ++rr) {
                const int row = bm + mf * 16 + rg + rr;
                if (row < QTOT) out[(size_t)row * 256 + col] = acc[mf][rr] + bb;
            }
    }
}

// ---------------------------------------------------------------------------
extern "C" void kernel_launch(void* const* d_in, const int* in_sizes, int n_in,
                              void* d_out, int out_size, void* d_ws, size_t ws_size,
                              hipStream_t stream) {
    const float* query  = (const float*)d_in[0];
    const float* rp     = (const float*)d_in[1];
    const float* inflat = (const float*)d_in[2];
    const int*   sp     = (const int*)d_in[3];
    const int*   lsi    = (const int*)d_in[4];
    const float* W_off  = (const float*)d_in[5];
    const float* b_off  = (const float*)d_in[6];
    const float* W_attn = (const float*)d_in[7];
    const float* b_attn = (const float*)d_in[8];
    const float* W_val  = (const float*)d_in[9];
    const float* b_val  = (const float*)d_in[10];
    const float* W_out  = (const float*)d_in[11];
    const float* b_out  = (const float*)d_in[12];
    float* out = (float*)d_out;

    char* ws = (char*)d_ws;
    ushort_t* projb  = (ushort_t*)ws; ws += (size_t)QTOT * 256 * 2;
    ushort_t* offb   = (ushort_t*)ws; ws += (size_t)QTOT * 256 * 2;
    float*    logitf = (float*)ws;    ws += (size_t)QTOT * 128 * 4;
    ushort_t* outpre = (ushort_t*)ws; ws += (size_t)QTOT * 256 * 2;
    ushort_t* WvT    = (ushort_t*)ws; ws += 65536 * 2;
    ushort_t* WcT    = (ushort_t*)ws; ws += 98304 * 2;
    ushort_t* WoT    = (ushort_t*)ws; ws += 65536 * 2;
    float*    bcomb  = (float*)ws;    ws += 384 * 4;

    prep<<<dim3(898), dim3(256), 0, stream>>>(W_val, W_off, W_attn, W_out, b_off, b_attn,
                                              WvT, WcT, WoT, bcomb);

    gemm1<<<dim3(766), dim3(256), 0, stream>>>(inflat, query, WvT, WcT, b_val, bcomb,
                                               projb, offb, logitf);

    sample6<<<dim3(3060), dim3(256), 0, stream>>>(rp, offb, logitf, projb, sp, lsi, outpre);

    gemm_o<<<dim3(383), dim3(256), 0, stream>>>(outpre, WoT, b_out, out);
}

// Round 13
// 67.034 us; speedup vs baseline: 1.2279x; 1.0282x over previous
//
#include <hip/hip_runtime.h>

#define QTOT 12240
#define KD   256

typedef float f32x4 __attribute__((ext_vector_type(4)));
typedef short s16x8 __attribute__((ext_vector_type(8)));
typedef short s16x4 __attribute__((ext_vector_type(4)));
typedef unsigned short ushort_t;

__device__ __forceinline__ unsigned short f2b(float x) {
    union { float f; unsigned u; } c; c.f = x;
    unsigned r = c.u + 0x7fffu + ((c.u >> 16) & 1u);
    return (unsigned short)(r >> 16);
}
__device__ __forceinline__ float b2f(unsigned short u) {
    return __uint_as_float((unsigned)u << 16);
}
// LDS row: 512B, XOR bits 4-6 of k-byte with row&7 (write & read sides).
__device__ __forceinline__ int swz(int row, int kb) { return row * 512 + (kb ^ ((row & 7) << 4)); }

// ---------------------------------------------------------------------------
// prep: weight transpose+bf16, combined off/attn bias (verified)
// ---------------------------------------------------------------------------
__global__ __launch_bounds__(256) void prep(
    const float* __restrict__ W_val, const float* __restrict__ W_off,
    const float* __restrict__ W_attn, const float* __restrict__ W_out,
    const float* __restrict__ b_off, const float* __restrict__ b_attn,
    ushort_t* __restrict__ WvT, ushort_t* __restrict__ WcT,
    ushort_t* __restrict__ WoT, float* __restrict__ bcomb)
{
    int id = blockIdx.x * 256 + threadIdx.x;
    if (id < 65536) { int n = id >> 8, k = id & 255; WvT[id] = f2b(W_val[k * 256 + n]); }
    else if (id < 163840) {
        int t = id - 65536; int n = t >> 8, k = t & 255;
        float v = (n < 256) ? W_off[k * 256 + n] : W_attn[k * 128 + (n - 256)];
        WcT[t] = f2b(v);
    } else if (id < 229376) {
        int t = id - 163840; int n = t >> 8, k = t & 255;
        WoT[t] = f2b(W_out[k * 256 + n]);
    } else if (id < 229760) {
        int t = id - 229376; bcomb[t] = (t < 256) ? b_off[t] : b_attn[t - 256];
    }
}

// ---------------------------------------------------------------------------
// gemm1: champion structure (A-read-once, B-in-registers, 1 barrier) with
// FUSED SOFTMAX epilogue for the attn-logit chunks (c=4,5 of off/attn
// blocks). MFMA C-layout puts a (row, head)'s 16 logits across one 16-lane
// group (col-in-head = lane&15), so softmax = 4x shfl_xor max + 4x sum.
// Stores softmaxed attn weights bf16 -> attnb (Q x 128).
// ---------------------------------------------------------------------------
__global__ __launch_bounds__(256) void gemm1(
    const float* __restrict__ inflat, const float* __restrict__ query,
    const ushort_t* __restrict__ WvT, const ushort_t* __restrict__ WcT,
    const float* __restrict__ b_val, const float* __restrict__ bcomb,
    ushort_t* __restrict__ projb, ushort_t* __restrict__ offb,
    ushort_t* __restrict__ attnb)
{
    __shared__ char As[16384];
    const int b = blockIdx.x;
    const bool isval = b < 383;
    const int bm = (isval ? b : b - 383) * 32;
    const float* A = isval ? inflat : query;
    const ushort_t* WT = isval ? WvT : WcT;
    const int nc = isval ? 4 : 6;

    const int tid = threadIdx.x, lane = tid & 63, wave = tid >> 6;
    const int lr = lane & 15, g8 = (lane >> 4) * 8;

    {   // stage A panel: 32 rows x 256 k, f32 -> bf16; linear coalesced map
        const float4* srcb = (const float4*)(A + (size_t)bm * KD);
        const int rem_rows = QTOT - bm;
#pragma unroll
        for (int j = 0; j < 8; ++j) {
            const int f4i = j * 256 + tid;
            const int row = f4i >> 6;
            const int colb = (f4i & 63) * 8;
            float4 f = make_float4(0.f, 0.f, 0.f, 0.f);
            if (row < rem_rows) f = srcb[f4i];
            s16x4 v;
            v[0] = f2b(f.x); v[1] = f2b(f.y); v[2] = f2b(f.z); v[3] = f2b(f.w);
            *(s16x4*)(As + swz(row, colb)) = v;
        }
    }
    __syncthreads();

    const int rg = (lane >> 4) * 4;

    for (int c = 0; c < nc; ++c) {
        const int col = c * 64 + wave * 16 + lr;
        s16x8 bfr[8];
        {
            const ushort_t* bp = WT + (size_t)col * KD + g8;
#pragma unroll
            for (int kc = 0; kc < 8; ++kc) bfr[kc] = *(const s16x8*)(bp + kc * 32);
        }
        f32x4 acc[2];
        acc[0] = (f32x4)0.f; acc[1] = (f32x4)0.f;
#pragma unroll
        for (int kc = 0; kc < 8; ++kc) {
            const int kb = (kc * 32 + g8) * 2;
            s16x8 a0 = *(const s16x8*)(As + swz(lr,      kb));
            s16x8 a1 = *(const s16x8*)(As + swz(16 + lr, kb));
            acc[0] = __builtin_amdgcn_mfma_f32_16x16x32_bf16(a0, bfr[kc], acc[0], 0, 0, 0);
            acc[1] = __builtin_amdgcn_mfma_f32_16x16x32_bf16(a1, bfr[kc], acc[1], 0, 0, 0);
        }
        const float bb = isval ? b_val[col] : bcomb[col];

        if (!isval && c >= 4) {
            // ---- fused softmax over the 16-lane group (cols of one head) ----
            const int gh = (c - 4) * 4 + wave;       // global head 0..7
            float v[2][4], m[2][4], e[2][4], s[2][4];
#pragma unroll
            for (int mf = 0; mf < 2; ++mf)
#pragma unroll
                for (int rr = 0; rr < 4; ++rr) { v[mf][rr] = acc[mf][rr] + bb; m[mf][rr] = v[mf][rr]; }
#pragma unroll
            for (int d = 1; d < 16; d <<= 1)
#pragma unroll
                for (int mf = 0; mf < 2; ++mf)
#pragma unroll
                    for (int rr = 0; rr < 4; ++rr) m[mf][rr] = fmaxf(m[mf][rr], __shfl_xor(m[mf][rr], d));
#pragma unroll
            for (int mf = 0; mf < 2; ++mf)
#pragma unroll
                for (int rr = 0; rr < 4; ++rr) { e[mf][rr] = __expf(v[mf][rr] - m[mf][rr]); s[mf][rr] = e[mf][rr]; }
#pragma unroll
            for (int d = 1; d < 16; d <<= 1)
#pragma unroll
                for (int mf = 0; mf < 2; ++mf)
#pragma unroll
                    for (int rr = 0; rr < 4; ++rr) s[mf][rr] += __shfl_xor(s[mf][rr], d);
#pragma unroll
            for (int mf = 0; mf < 2; ++mf)
#pragma unroll
                for (int rr = 0; rr < 4; ++rr) {
                    const int row = bm + mf * 16 + rg + rr;
                    if (row < QTOT)
                        attnb[(size_t)row * 128 + gh * 16 + lr] = f2b(e[mf][rr] / s[mf][rr]);
                }
        } else {
#pragma unroll
            for (int mf = 0; mf < 2; ++mf)
#pragma unroll
                for (int rr = 0; rr < 4; ++rr) {
                    const int row = bm + mf * 16 + rg + rr;
                    if (row >= QTOT) continue;
                    const float v = acc[mf][rr] + bb;
                    if (isval) projb[(size_t)row * 256 + col] = f2b(v);
                    else       offb [(size_t)row * 256 + col] = f2b(v);
                }
        }
    }
}

// ---------------------------------------------------------------------------
// sample6: head-half split (R12 champion), metadata simplified — attn
// weights arrive pre-softmaxed (bf16) from gemm1.
// ---------------------------------------------------------------------------
__global__ __launch_bounds__(256) void sample6(
    const float* __restrict__ rp, const ushort_t* __restrict__ offb,
    const ushort_t* __restrict__ attnb, const ushort_t* __restrict__ projb,
    const int* __restrict__ sp, const int* __restrict__ lsi,
    ushort_t* __restrict__ outpre)
{
    const int bid = blockIdx.x;
    const int hh = (bid >= 1530) ? 1 : 0;       // head-half (slow index)
    const int g  = hh ? (bid - 1530) : bid;     // query group
    const int q0 = g * 8;
    const int tid = threadIdx.x;

    __shared__ int   s_idx[512][4];
    __shared__ float s_w[512][4];

    // ---- metadata: 512 tasks = (ql 0..7, h' 0..3, l 0..3, p 0..3) ----
#pragma unroll
    for (int rep = 0; rep < 2; ++rep) {
        const int task = rep * 256 + tid;
        const int ql = task >> 6;
        const int hp = (task >> 4) & 3;
        const int lp = task & 15;
        const int l = lp >> 2;
        const int q = q0 + ql;
        const int gh = hh * 4 + hp;
        const int t128 = gh * 16 + lp;

        const float aw = b2f(attnb[(size_t)q * 128 + t128]);

        const unsigned opk = *(const unsigned*)&offb[(size_t)q * 256 + t128 * 2];
        const float ox = __uint_as_float(opk << 16);
        const float oy = __uint_as_float(opk & 0xffff0000u);

        const int Hl = sp[l * 2], Wl = sp[l * 2 + 1], st = lsi[l];
        const float rx = rp[((size_t)q * 4 + l) * 2 + 0];
        const float ry = rp[((size_t)q * 4 + l) * 2 + 1];

        const float x = rx * (float)Wl + ox - 0.5f;
        const float y = ry * (float)Hl + oy - 0.5f;
        const float xf = floorf(x), yf = floorf(y);
        const int x0 = (int)xf, y0 = (int)yf;
        const float lx = x - xf, ly = y - yf;

        const bool vx0 = (x0 >= 0) && (x0 < Wl);
        const bool vx1 = (x0 + 1 >= 0) && (x0 + 1 < Wl);
        const bool vy0 = (y0 >= 0) && (y0 < Hl);
        const bool vy1 = (y0 + 1 >= 0) && (y0 + 1 < Hl);

        s_w[task][0] = (vx0 && vy0) ? aw * (1.f - ly) * (1.f - lx) : 0.f;
        s_w[task][1] = (vx1 && vy0) ? aw * (1.f - ly) * lx         : 0.f;
        s_w[task][2] = (vx0 && vy1) ? aw * ly * (1.f - lx)         : 0.f;
        s_w[task][3] = (vx1 && vy1) ? aw * ly * lx                 : 0.f;
        s_idx[task][0] = (vx0 && vy0) ? (st + y0 * Wl + x0) * 512           : 0;
        s_idx[task][1] = (vx1 && vy0) ? (st + y0 * Wl + x0 + 1) * 512       : 0;
        s_idx[task][2] = (vx0 && vy1) ? (st + (y0 + 1) * Wl + x0) * 512     : 0;
        s_idx[task][3] = (vx1 && vy1) ? (st + (y0 + 1) * Wl + x0 + 1) * 512 : 0;
    }
    __syncthreads();

    // ---- gathers: thread = (ql 0..7, h' 0..3, pq 0..1, c8 0..3) ----
    const int c8 = tid & 3;
    const int pq = (tid >> 2) & 1;
    const int hp = (tid >> 3) & 3;
    const int ql = tid >> 5;
    const int gh = hh * 4 + hp;
    const char* basec = (const char*)projb + (gh * 32 + c8 * 8) * 2;
    const int slot0 = (ql << 6) | (hp << 4);

    float a0 = 0, a1 = 0, a2 = 0, a3 = 0, a4 = 0, a5 = 0, a6 = 0, a7 = 0;
#pragma unroll
    for (int l = 0; l < 4; ++l) {
#pragma unroll
        for (int j = 0; j < 2; ++j) {
            const int slot = slot0 | (l << 2) | (pq * 2 + j);
            const int4   i4 = *(const int4*)s_idx[slot];
            const float4 w4 = *(const float4*)s_w[slot];
#pragma unroll
            for (int c = 0; c < 4; ++c) {
                const int   id = (c == 0) ? i4.x : (c == 1) ? i4.y : (c == 2) ? i4.z : i4.w;
                const float w  = (c == 0) ? w4.x : (c == 1) ? w4.y : (c == 2) ? w4.z : w4.w;
                const uint4 v = *(const uint4*)(basec + id);
                a0 += w * __uint_as_float(v.x << 16);
                a1 += w * __uint_as_float(v.x & 0xffff0000u);
                a2 += w * __uint_as_float(v.y << 16);
                a3 += w * __uint_as_float(v.y & 0xffff0000u);
                a4 += w * __uint_as_float(v.z << 16);
                a5 += w * __uint_as_float(v.z & 0xffff0000u);
                a6 += w * __uint_as_float(v.w << 16);
                a7 += w * __uint_as_float(v.w & 0xffff0000u);
            }
        }
    }
    a0 += __shfl_xor(a0, 4); a1 += __shfl_xor(a1, 4);
    a2 += __shfl_xor(a2, 4); a3 += __shfl_xor(a3, 4);
    a4 += __shfl_xor(a4, 4); a5 += __shfl_xor(a5, 4);
    a6 += __shfl_xor(a6, 4); a7 += __shfl_xor(a7, 4);

    if (pq == 0) {
        uint4 o;
        o.x = (unsigned)f2b(a0) | ((unsigned)f2b(a1) << 16);
        o.y = (unsigned)f2b(a2) | ((unsigned)f2b(a3) << 16);
        o.z = (unsigned)f2b(a4) | ((unsigned)f2b(a5) << 16);
        o.w = (unsigned)f2b(a6) | ((unsigned)f2b(a7) << 16);
        *(uint4*)&outpre[(size_t)(q0 + ql) * 256 + gh * 32 + c8 * 8] = o;
    }
}

// ---------------------------------------------------------------------------
// gemm_o: unchanged champion (LDS-free, barrier-free, BM=32, N=256).
// ---------------------------------------------------------------------------
__global__ __launch_bounds__(256) void gemm_o(
    const ushort_t* __restrict__ Ab, const ushort_t* __restrict__ WoT,
    const float* __restrict__ b_out, float* __restrict__ out)
{
    const int bm = blockIdx.x * 32;
    const int tid = threadIdx.x, lane = tid & 63, wave = tid >> 6;
    const int lr = lane & 15, g8 = (lane >> 4) * 8;
    const int rg = (lane >> 4) * 4;

    const ushort_t* ap0;
    const ushort_t* ap1;
    {
        int r0 = bm + lr;      if (r0 >= QTOT) r0 = QTOT - 1;
        int r1 = bm + 16 + lr; if (r1 >= QTOT) r1 = QTOT - 1;
        ap0 = Ab + (size_t)r0 * KD + g8;
        ap1 = Ab + (size_t)r1 * KD + g8;
    }

#pragma unroll
    for (int c = 0; c < 4; ++c) {
        const int col = c * 64 + wave * 16 + lr;
        s16x8 bfr[8];
        {
            const ushort_t* bp = WoT + (size_t)col * KD + g8;
#pragma unroll
            for (int kc = 0; kc < 8; ++kc) bfr[kc] = *(const s16x8*)(bp + kc * 32);
        }
        f32x4 acc[2];
        acc[0] = (f32x4)0.f; acc[1] = (f32x4)0.f;
#pragma unroll
        for (int kc = 0; kc < 8; ++kc) {
            s16x8 a0 = *(const s16x8*)(ap0 + kc * 32);
            s16x8 a1 = *(const s16x8*)(ap1 + kc * 32);
            acc[0] = __builtin_amdgcn_mfma_f32_16x16x32_bf16(a0, bfr[kc], acc[0], 0, 0, 0);
            acc[1] = __builtin_amdgcn_mfma_f32_16x16x32_bf16(a1, bfr[kc], acc[1], 0, 0, 0);
        }
        const float bb = b_out[col];
#pragma unroll
        for (int mf = 0; mf < 2; ++mf)
#pragma unroll
            for (int rr = 0; rr < 4; ++rr) {
                const int row = bm + mf * 16 + rg + rr;
                if (row < QTOT) out[(size_t)row * 256 + col] = acc[mf][rr] + bb;
            }
    }
}

// ---------------------------------------------------------------------------
extern "C" void kernel_launch(void* const* d_in, const int* in_sizes, int n_in,
                              void* d_out, int out_size, void* d_ws, size_t ws_size,
                              hipStream_t stream) {
    const float* query  = (const float*)d_in[0];
    const float* rp     = (const float*)d_in[1];
    const float* inflat = (const float*)d_in[2];
    const int*   sp     = (const int*)d_in[3];
    const int*   lsi    = (const int*)d_in[4];
    const float* W_off  = (const float*)d_in[5];
    const float* b_off  = (const float*)d_in[6];
    const float* W_attn = (const float*)d_in[7];
    const float* b_attn = (const float*)d_in[8];
    const float* W_val  = (const float*)d_in[9];
    const float* b_val  = (const float*)d_in[10];
    const float* W_out  = (const float*)d_in[11];
    const float* b_out  = (const float*)d_in[12];
    float* out = (float*)d_out;

    char* ws = (char*)d_ws;
    ushort_t* projb  = (ushort_t*)ws; ws += (size_t)QTOT * 256 * 2;
    ushort_t* offb   = (ushort_t*)ws; ws += (size_t)QTOT * 256 * 2;
    ushort_t* attnb  = (ushort_t*)ws; ws += (size_t)QTOT * 128 * 2;
    ushort_t* outpre = (ushort_t*)ws; ws += (size_t)QTOT * 256 * 2;
    ushort_t* WvT    = (ushort_t*)ws; ws += 65536 * 2;
    ushort_t* WcT    = (ushort_t*)ws; ws += 98304 * 2;
    ushort_t* WoT    = (ushort_t*)ws; ws += 65536 * 2;
    float*    bcomb  = (float*)ws;    ws += 384 * 4;

    prep<<<dim3(898), dim3(256), 0, stream>>>(W_val, W_off, W_attn, W_out, b_off, b_attn,
                                              WvT, WcT, WoT, bcomb);

    gemm1<<<dim3(766), dim3(256), 0, stream>>>(inflat, query, WvT, WcT, b_val, bcomb,
                                               projb, offb, attnb);

    sample6<<<dim3(3060), dim3(256), 0, stream>>>(rp, offb, attnb, projb, sp, lsi, outpre);

    gemm_o<<<dim3(383), dim3(256), 0, stream>>>(outpre, WoT, b_out, out);
}